// Round 9
// baseline (324.000 us; speedup 1.0000x reference)
//
#include <hip/hip_runtime.h>
#include <hip/hip_bf16.h>
#include <math.h>

#define VV 50257   // vocab
#define VP 50304   // vocab padded to multiple of 128 (and 16)
#define HH 512     // d_model
#define SS 512     // source length
#define BB 8       // batch
#define TT 64      // decode steps
#define MM (TT*BB) // 512 GEMM rows

typedef __bf16 bf16x2 __attribute__((ext_vector_type(2)));
typedef __bf16 bf16x4 __attribute__((ext_vector_type(4)));
typedef __bf16 bf16x8 __attribute__((ext_vector_type(8)));
typedef float  f32x4  __attribute__((ext_vector_type(4)));
// under-aligned float4: W rows are only 4B-aligned (VV odd)
typedef float f4u __attribute__((vector_size(16), aligned(4)));

// fp32 -> bf16 RNE
__device__ __forceinline__ __bf16 f2b(float f) {
    unsigned u = __builtin_bit_cast(unsigned, f);
    unsigned r = (u + 0x7fffu + ((u >> 16) & 1u)) >> 16;
    unsigned short s = (unsigned short)r;
    return __builtin_bit_cast(__bf16, s);
}

// async global->LDS, 16B per lane; lds base must be wave-uniform
__device__ __forceinline__ void gl2lds16(const void* g, void* l) {
    __builtin_amdgcn_global_load_lds(
        (const __attribute__((address_space(1))) unsigned*)g,
        (__attribute__((address_space(3))) unsigned*)l, 16, 0, 0);
}

#define WAITV(n) asm volatile("s_waitcnt vmcnt(" #n ")" ::: "memory")

// ---------------------------------------------------------------------------
// L1 (single pre-pass, no LDS, no barriers):
//  blocks [0,3200):        W fp32 [HH][VV] -> Wt8 bf16 [64][VP][8] k8-panels
//  blocks [3200,3456):     cast decode_output fp32 -> bf16
//  blocks [3456,4480):     mw[s,b] = dot(memory[s,b,:], W_prob)
//  block  4480:            Z[0..MM) = 0   (replaces hipMemsetAsync)
// ---------------------------------------------------------------------------
#define NW8 3200   // 50 n-chunks x 64 k8-panels
__global__ __launch_bounds__(256) void k_pre(const float* __restrict__ W,
                                             __bf16* __restrict__ Wt8,
                                             const float* __restrict__ A,
                                             __bf16* __restrict__ Ab,
                                             const float* __restrict__ mem,
                                             const float* __restrict__ Wp,
                                             float* __restrict__ mw,
                                             float* __restrict__ Z) {
    int tid = threadIdx.x;
    int bx = blockIdx.x;
    if (bx < NW8) {
        int cx = bx % 50, kb = bx / 50;
        int nb = cx * 1024 + tid * 4;
        if (nb >= VP) return;               // last chunk overhang
        const float* Wr = W + (size_t)(kb * 8) * VV + nb;
        float v[8][4];
        if (nb + 4 <= VV) {
#pragma unroll
            for (int r = 0; r < 8; r++) {
                f4u x = *(const f4u*)(Wr + (size_t)r * VV);
#pragma unroll
                for (int j = 0; j < 4; j++) v[r][j] = x[j];
            }
        } else {
#pragma unroll
            for (int r = 0; r < 8; r++)
#pragma unroll
                for (int j = 0; j < 4; j++)
                    v[r][j] = (nb + j < VV) ? Wr[(size_t)r * VV + j] : 0.f;
        }
#pragma unroll
        for (int j = 0; j < 4; j++) {
            bf16x8 o = {f2b(v[0][j]), f2b(v[1][j]), f2b(v[2][j]), f2b(v[3][j]),
                        f2b(v[4][j]), f2b(v[5][j]), f2b(v[6][j]), f2b(v[7][j])};
            *(bf16x8*)&Wt8[((size_t)kb * VP + nb + j) * 8] = o;
        }
    } else if (bx < NW8 + 256) {
        int i = ((bx - NW8) * 256 + tid) * 4;
        float4 va = *(const float4*)&A[i];
        bf16x4 o = {f2b(va.x), f2b(va.y), f2b(va.z), f2b(va.w)};
        *(bf16x4*)&Ab[i] = o;
    } else if (bx < NW8 + 256 + 1024) {
        int bxm = bx - (NW8 + 256);
        int row = bxm * 4 + (tid >> 6);      // 0..4095
        int lane = tid & 63;
        const float* mp = mem + (size_t)row * HH;
        float acc = 0.f;
#pragma unroll
        for (int i = 0; i < HH / 64; i++)
            acc += mp[lane + 64 * i] * Wp[lane + 64 * i];
#pragma unroll
        for (int off = 32; off > 0; off >>= 1) acc += __shfl_down(acc, off);
        if (lane == 0) mw[row] = acc;
    } else {
        Z[tid] = 0.f;
        Z[tid + 256] = 0.f;
    }
}

// ---------------------------------------------------------------------------
// K3: MFMA GEMM, tile BM=256 x BN=128, BK=32, 16 k-iters. NOW: depth-3
// pipeline — 4 LDS buffers per operand (97 KB -> 1 block/CU), 16 waves
// (1024 thr, wave tile 64x32, acc[4][2] — R1-validated mapping) so 16
// waves/CU is preserved while prefetch flight goes 2 -> 3 iterations.
// Waves 0-7 stage {A seg w, B seg w} (2 loads/round -> WAITV(4) steady);
// waves 8-15 stage {A seg w} (1 load/round -> WAITV(2) steady). Counted
// vmcnt never drains to 0 in the main loop. k-accumulation order per output
// fragment unchanged -> bit-identical C vs round 8.
// ---------------------------------------------------------------------------
template<bool BF16OUT>
__global__ __launch_bounds__(1024, 4) void k_gemm8(const __bf16* __restrict__ Ab,
                                                   const __bf16* __restrict__ Wt8,
                                                   const float* __restrict__ bias,
                                                   float* __restrict__ Cf,
                                                   __bf16* __restrict__ Cb,
                                                   float* __restrict__ Zrow) {
    __shared__ __bf16 As[4][8192];   // 4 bufs x 16KB: 16 segs x 16 rows x 32k
    __shared__ __bf16 Bs[4][4096];   // 4 bufs x 8KB:   8 segs
    __shared__ float zred[256];

    const int tid  = threadIdx.x;
    const int lane = tid & 63;
    const int wave = tid >> 6;          // 0..15
    const int l15  = lane & 15;
    const int quad = lane >> 4;
    const int wr = (wave >> 2) * 64;    // 0,64,128,192
    const int wc = (wave & 3) * 32;     // 0,32,64,96

    // bijective XCD swizzle over the 786-block grid (q=98, r=2)
    int L = blockIdx.x + gridDim.x * blockIdx.y;
    int xcd = L & 7, i8 = L >> 3;
    int nid = (xcd < 2 ? xcd * 99 : 2 * 99 + (xcd - 2) * 98) + i8;
    const int row0 = (nid & 1) * 256;   // row fastest: B-panel L2 reuse
    const int col0 = (nid >> 1) * 128;

    // A: wave w stages seg w (16 segs); B: waves 0-7 stage seg w (8 segs).
    const size_t offA = (size_t)(row0 + wave * 16 + l15) * HH + quad * 8;
    const size_t offB = (size_t)quad * VP * 8 +
                        (size_t)(col0 + (wave & 7) * 16 + l15) * 8;

#define STAGE(buf, k0)                                                      \
    do {                                                                    \
        gl2lds16(Ab + offA + (k0), &As[buf][wave * 512]);                   \
        if (wave < 8)                                                       \
            gl2lds16(Wt8 + offB + (size_t)(k0) * VP, &Bs[buf][wave * 512]); \
    } while (0)

    f32x4 acc[4][2] = {};

    STAGE(0, 0);
    STAGE(1, 32);
    STAGE(2, 64);
#pragma unroll
    for (int it = 0; it < 16; ++it) {
        if (wave < 8) {       // 2 loads/round class
            if (it <= 13)      WAITV(4);   // tiles it+1,it+2 stay in flight
            else if (it == 14) WAITV(2);
            else               WAITV(0);
        } else {              // 1 load/round class
            if (it <= 13)      WAITV(2);
            else if (it == 14) WAITV(1);
            else               WAITV(0);
        }
        __builtin_amdgcn_s_barrier();
        if (it <= 12) STAGE((it + 3) & 3, (it + 3) * 32);
        const __bf16* Al = &As[it & 3][0];
        const __bf16* Bl = &Bs[it & 3][0];
        bf16x8 af[4], bfv[2];
#pragma unroll
        for (int mt = 0; mt < 4; mt++)
            af[mt] = *(const bf16x8*)&Al[((wr >> 4) + mt) * 512 + lane * 8];
#pragma unroll
        for (int nt = 0; nt < 2; nt++)
            bfv[nt] = *(const bf16x8*)&Bl[((wc >> 4) + nt) * 512 + lane * 8];
        __builtin_amdgcn_s_setprio(1);
#pragma unroll
        for (int mt = 0; mt < 4; mt++)
#pragma unroll
            for (int nt = 0; nt < 2; nt++)
                acc[mt][nt] = __builtin_amdgcn_mfma_f32_16x16x32_bf16(
                    af[mt], bfv[nt], acc[mt][nt], 0, 0, 0);
        __builtin_amdgcn_s_setprio(0);
    }
#undef STAGE

    __syncthreads();
    if (tid < 256) zred[tid] = 0.f;
    __syncthreads();

#pragma unroll
    for (int mt = 0; mt < 4; mt++) {
        float esum[4] = {0.f, 0.f, 0.f, 0.f};
#pragma unroll
        for (int nt = 0; nt < 2; nt++) {
            int c = col0 + wc + nt * 16 + l15;
            if (c < VV) {
                float bv = bias[c];
#pragma unroll
                for (int i = 0; i < 4; i++) {
                    int r = row0 + wr + mt * 16 + quad * 4 + i;
                    float l = acc[mt][nt][i] + bv;
                    if (BF16OUT) Cb[(size_t)r * VP + c] = f2b(l);
                    else         Cf[(size_t)r * VV + c] = l;
                    esum[i] += __expf(l);
                }
            }
        }
#pragma unroll
        for (int i = 0; i < 4; i++) {
            float e = esum[i];
            e += __shfl_xor(e, 1);
            e += __shfl_xor(e, 2);
            e += __shfl_xor(e, 4);
            e += __shfl_xor(e, 8);
            if (l15 == 0)
                atomicAdd(&zred[wr + mt * 16 + quad * 4 + i], e);
        }
    }
    __syncthreads();
    if (tid < 256) atomicAdd(&Zrow[row0 + tid], zred[tid]);
}

// ---------------------------------------------------------------------------
// K4 shared preamble (256-thread version, used by fallback k_final_s)
// ---------------------------------------------------------------------------
#define HT 1024
#define NBW 1572   // ceil(VV/32)

__device__ __forceinline__ void build_hash(const int* __restrict__ src,
                                           const float* __restrict__ ap,
                                           int b, int tid,
                                           int* keys, float* vals, unsigned* bmap,
                                           float* red, int* s_D, float* s_Zc) {
    for (int i = tid; i < HT; i += 256) { keys[i] = -1; vals[i] = 0.f; }
    for (int i = tid; i < NBW; i += 256) bmap[i] = 0u;
    if (tid == 0) *s_D = 0;
    __syncthreads();

    for (int s = tid; s < SS; s += 256) {
        int idx = src[s * BB + b];
        float v = ap[s];
        unsigned h = ((unsigned)idx * 2654435761u) >> 22;
        while (true) {
            int old = atomicCAS(&keys[h], -1, idx);
            if (old == -1 || old == idx) { atomicAdd(&vals[h], v); break; }
            h = (h + 1) & (HT - 1);
        }
    }
    __syncthreads();

    float lsum = 0.f; int dloc = 0;
    for (int i = tid; i < HT; i += 256) {
        int k = keys[i];
        if (k != -1) {
            lsum += __expf(vals[i]); dloc++;
            atomicOr(&bmap[(unsigned)k >> 5], 1u << (k & 31));
        }
    }
    atomicAdd(s_D, dloc);
    red[tid] = lsum; __syncthreads();
    for (int st = 128; st > 0; st >>= 1) {
        if (tid < st) red[tid] += red[tid + st];
        __syncthreads();
    }
    if (tid == 0) *s_Zc = (float)(VV - *s_D) + red[0];
    __syncthreads();
}

// ---------------------------------------------------------------------------
// K4a: finalize from bf16 padded logits. ONE block per row (hash built once,
// was 2x), 1024 threads; block computes its own prob. Clean 8-packs (bitmap
// byte==0, ~92%) take a guard-free path.
// ---------------------------------------------------------------------------
__global__ __launch_bounds__(1024) void k_final3(const int* __restrict__ src,
                                                 const float* __restrict__ attn,
                                                 const float* __restrict__ mw,
                                                 const float* __restrict__ bp,
                                                 const float* __restrict__ Zrow,
                                                 const __bf16* __restrict__ LG,
                                                 float* __restrict__ out) {
    __shared__ int      keys[HT];
    __shared__ float    vals[HT];
    __shared__ unsigned bmap[NBW];
    __shared__ float    red[1024];
    __shared__ float    red2[1024];
    __shared__ int      s_D;
    __shared__ float    s_Zc;
    __shared__ float    s_p;

    int r = blockIdx.x;
    int t = r / BB, b = r % BB;
    int tid = threadIdx.x;
    const float* ap = attn + ((size_t)b * TT + t) * SS;

    // ---- build hash (1024 threads; HT == 1024) + prob partial ----
    { keys[tid] = -1; vals[tid] = 0.f; }
    for (int i = tid; i < NBW; i += 1024) bmap[i] = 0u;
    if (tid == 0) s_D = 0;
    __syncthreads();

    float pv = 0.f;
    if (tid < SS) {
        int idx = src[tid * BB + b];
        float av = ap[tid];
        pv = av * mw[tid * BB + b];
        unsigned h = ((unsigned)idx * 2654435761u) >> 22;
        while (true) {
            int old = atomicCAS(&keys[h], -1, idx);
            if (old == -1 || old == idx) { atomicAdd(&vals[h], av); break; }
            h = (h + 1) & (HT - 1);
        }
    }
    __syncthreads();

    float lsum = 0.f;
    {
        int k = keys[tid];
        bool occ = (k != -1);
        if (occ) {
            lsum = __expf(vals[tid]);
            atomicOr(&bmap[(unsigned)k >> 5], 1u << (k & 31));
        }
        unsigned long long m = __ballot(occ);
        if ((tid & 63) == 0) atomicAdd(&s_D, __popcll(m));
    }
    red[tid] = lsum; red2[tid] = pv; __syncthreads();
    for (int st = 512; st > 0; st >>= 1) {
        if (tid < st) { red[tid] += red[tid + st]; red2[tid] += red2[tid + st]; }
        __syncthreads();
    }
    if (tid == 0) {
        s_Zc = (float)(VV - s_D) + red[0];
        s_p  = 1.f / (1.f + expf(-(red2[0] + bp[0])));
    }
    __syncthreads();

    float p = s_p;
    float pinvZ = p / Zrow[r];
    float qinvZc = (1.f - p) / s_Zc;

    const __bf16* lrow = LG + (size_t)r * VP;
    float* orow = out + (size_t)r * VV;

    for (int v0 = tid * 8; v0 < VP; v0 += 8192) {
        bf16x8 l8 = *(const bf16x8*)&lrow[v0];
        unsigned bits = (bmap[v0 >> 5] >> (v0 & 31)) & 0xFFu;  // v0%8==0
        if (bits == 0u && v0 + 8 <= VV) {
#pragma unroll
            for (int e = 0; e < 8; e++)
                orow[v0 + e] = __logf(pinvZ * __expf((float)l8[e]) + qinvZc);
        } else {
#pragma unroll
            for (int e = 0; e < 8; e++) {
                int v = v0 + e;
                if (v < VV) {
                    float l = (float)l8[e];
                    float c = 1.f;
                    if ((bits >> e) & 1u) {
                        unsigned h = ((unsigned)v * 2654435761u) >> 22;
                        while (true) {
                            int k = keys[h];
                            if (k == v) { c = __expf(vals[h]); break; }
                            if (k == -1) break;
                            h = (h + 1) & (HT - 1);
                        }
                    }
                    orow[v] = __logf(pinvZ * __expf(l) + qinvZc * c);
                }
            }
        }
    }
}

// ---------------------------------------------------------------------------
// K4b: fallback — finalize fp32 logits in-place in d_out (computes own prob)
// ---------------------------------------------------------------------------
#define CHUNKS 6283
__global__ __launch_bounds__(256) void k_final_s(const int* __restrict__ src,
                                                 const float* __restrict__ attn,
                                                 const float* __restrict__ mw,
                                                 const float* __restrict__ bp,
                                                 const float* __restrict__ Zrow,
                                                 float* __restrict__ out) {
    __shared__ int      keys[HT];
    __shared__ float    vals[HT];
    __shared__ unsigned bmap[NBW];
    __shared__ float    red[256];
    __shared__ int      s_D;
    __shared__ float    s_Zc;
    __shared__ float    s_p;

    int r = blockIdx.y;
    int t = r / BB, b = r % BB;
    int tid = threadIdx.x;
    const float* ap = attn + ((size_t)b * TT + t) * SS;

    float pacc = ap[tid] * mw[tid * BB + b] +
                 ap[tid + 256] * mw[(tid + 256) * BB + b];
    red[tid] = pacc; __syncthreads();
    for (int st = 128; st > 0; st >>= 1) {
        if (tid < st) red[tid] += red[tid + st];
        __syncthreads();
    }
    if (tid == 0) s_p = 1.f / (1.f + expf(-(red[0] + bp[0])));
    __syncthreads();

    build_hash(src, ap, b, tid, keys, vals, bmap, red, &s_D, &s_Zc);

    float p = s_p;
    float pinvZ = p / Zrow[r];
    float qinvZc = (1.f - p) / s_Zc;

    int c0 = blockIdx.x * CHUNKS;
    int c1 = c0 + CHUNKS; if (c1 > VV) c1 = VV;
    float* rowp = out + (size_t)r * VV;

    for (int v = c0 + tid; v < c1; v += 256) {
        float l = rowp[v];
        float c = 1.f;
        if ((bmap[v >> 5] >> (v & 31)) & 1u) {
            unsigned h = ((unsigned)v * 2654435761u) >> 22;
            while (true) {
                int k = keys[h];
                if (k == v) { c = __expf(vals[h]); break; }
                if (k == -1) break;
                h = (h + 1) & (HT - 1);
            }
        }
        rowp[v] = __logf(pinvZ * __expf(l) + qinvZc * c);
    }
}

// ---------------------------------------------------------------------------
extern "C" void kernel_launch(void* const* d_in, const int* in_sizes, int n_in,
                              void* d_out, int out_size, void* d_ws, size_t ws_size,
                              hipStream_t stream) {
    const int*   src_full      = (const int*)d_in[0];   // [S,B]
    const float* decode_output = (const float*)d_in[1]; // [T,B,H]
    const float* decode_attn   = (const float*)d_in[2]; // [B,T,S]
    const float* memory        = (const float*)d_in[3]; // [S,B,H]
    const float* W_gen         = (const float*)d_in[4]; // [H,V]
    const float* b_gen         = (const float*)d_in[5]; // [V]
    const float* W_prob        = (const float*)d_in[6]; // [H]
    const float* b_prob        = (const float*)d_in[7]; // [1]
    float* out = (float*)d_out;                         // [T,B,V]

    float* ws   = (float*)d_ws;
    float* mw   = ws;                        // 4096 floats
    float* Z    = ws + 4608;                 // 512
    __bf16* Ab  = (__bf16*)(ws + 5120);      // 512*512 bf16
    __bf16* Wt8 = (__bf16*)(ws + 5120 + 131072);   // 64*VP*8 bf16 (51.5 MB)
    __bf16* LG  = Wt8 + (size_t)VP * HH;           // MM*VP bf16 (51.5 MB)

    size_t base_b = (size_t)(5120 + 131072) * sizeof(float);
    size_t wt_b   = (size_t)VP * HH * 2;
    size_t lg_b   = (size_t)MM * VP * 2;
    bool full = ws_size >= base_b + wt_b + lg_b;

    // L1: Wt8 k8-panels (3200) + castA (256) + mw (1024) + Z-zero (1)
    k_pre<<<NW8 + 256 + 1024 + 1, 256, 0, stream>>>(
        W_gen, Wt8, decode_output, Ab, memory, W_prob, mw, Z);

    dim3 ggrid(MM / 256, VP / 128);          // (2, 393)
    if (full) {
        k_gemm8<true><<<ggrid, 1024, 0, stream>>>(Ab, Wt8, b_gen, nullptr, LG, Z);
        k_final3<<<MM, 1024, 0, stream>>>(src_full, decode_attn, mw, b_prob,
                                          Z, LG, out);
    } else {
        k_gemm8<false><<<ggrid, 1024, 0, stream>>>(Ab, Wt8, b_gen, out, nullptr, Z);
        dim3 fgrid((VV + CHUNKS - 1) / CHUNKS, MM);  // (8, 512)
        k_final_s<<<fgrid, 256, 0, stream>>>(src_full, decode_attn, mw, b_prob,
                                             Z, out);
    }
}